// Round 6
// baseline (1291.600 us; speedup 1.0000x reference)
//
#include <hip/hip_runtime.h>
#include <hip/hip_cooperative_groups.h>
namespace cg = cooperative_groups;

// Problem constants
#define BB   128
#define DD   2048
#define NN   2048
#define LL   4
#define OUTN 1024
#define NB   (NN * BB)
#define KC   32            // k per LDS chunk
#define PADW 34            // doubles per n-row in LDS W tile (32 + 2 pad)
#define NSPLIT  16
#define KRANGE  (DD / NSPLIT)    // 128
#define NCHUNK  (KRANGE / KC)    // 4

typedef double double4v __attribute__((ext_vector_type(4)));

// ===========================================================================
// FUSED cooperative kernel: gather0 -> [gemm -> spike] x4 -> out
// 1024 blocks x 256 threads, exactly 4 blocks/CU co-resident.
// gemm/spike bodies are the R4-proven versions (single-buffer LDS W tile,
// runtime D-layout probe, fixed-order split reduction).
// ===========================================================================
__global__ __launch_bounds__(256, 4) void mega_kernel(
    const float* __restrict__ x, const float* __restrict__ W,
    const float* __restrict__ thresholds, const int* __restrict__ axon,
    const int* __restrict__ oidx, const int* __restrict__ Tptr,
    float* __restrict__ out,
    float* __restrict__ At, float* __restrict__ meanT,
    float* __restrict__ cntT, double* __restrict__ parts)
{
    __shared__ __align__(16) double Wq[64 * PADW];   // 17.4 KB
    cg::grid_group grid = cg::this_grid();

    const int t    = threadIdx.x;
    const int bid  = blockIdx.x;          // 0..1023
    const int lane = t & 63;
    const int q    = lane >> 4;           // assumed k-quad
    const int c    = lane & 15;           // assumed m (A) / n (B) coordinate

    // ---- runtime D-layout probe (layout-agnostic store), once ----
    double4v pr = {0., 0., 0., 0.}, pc = {0., 0., 0., 0.};
    pr = __builtin_amdgcn_mfma_f64_16x16x4f64(0.25 * (double)c, 1.0, pr, 0, 0, 0);
    pc = __builtin_amdgcn_mfma_f64_16x16x4f64(0.25, (double)c, pc, 0, 0, 0);
    int rowD[4], colD[4];
    #pragma unroll
    for (int r = 0; r < 4; ++r) {
        rowD[r] = (int)(pr[r] + 0.25);
        colD[r] = (int)(pc[r] + 0.25);
    }

    // ---- phase 0: layer-0 transpose-gather At[k][b] = x[b, axon0[k]] ----
    {
        int i = bid * 256 + t;            // 1024*256 = DD*BB
        int k = i >> 7;
        int b = i & 127;
        At[i] = x[b * DD + axon[k]];
    }
    grid.sync();

    // gemm decomposition (fixed for all layers)
    const int nsup = bid & 31;
    const int bsup = (bid >> 5) & 1;
    const int split = bid >> 6;           // 0..15
    const int n0b  = nsup * 64;
    const int k0s  = split * KRANGE;
    const int wq   = t >> 6;
    const int b0w  = bsup * 64 + wq * 16;
    const int sn   = t >> 3;              // 0..31
    const int sm   = t & 7;               // 0..7
    const int T    = *Tptr;

    for (int l = 0; l < LL; ++l) {
        const float* srcT = (l == 0) ? At : meanT;
        const int*   idx  = (l == 0) ? nullptr : (axon + l * DD);
        const float* Wl   = W + (size_t)l * NN * DD;

        // ================= gemm phase (R4 body) =================
        double4v acc[4] = {{0.,0.,0.,0.},{0.,0.,0.,0.},{0.,0.,0.,0.},{0.,0.,0.,0.}};

        float4 a0 = *(const float4*)(Wl + (size_t)(n0b + sn) * DD + k0s + 4 * sm);
        float4 a1 = *(const float4*)(Wl + (size_t)(n0b + sn + 32) * DD + k0s + 4 * sm);
        float bF[8];
        #pragma unroll
        for (int j = 0; j < 8; ++j) {
            int k = k0s + 4 * j + q;
            int row = idx ? idx[k] : k;
            bF[j] = srcT[(size_t)row * BB + b0w + c];
        }

        for (int ch = 0; ch < NCHUNK; ++ch) {
            __syncthreads();               // previous chunk's readers done
            // stage A (cvt fp32->fp64): k_local = 4*sm + i at col sm + 8*i
            {
                const float* f0 = (const float*)&a0;
                const float* f1 = (const float*)&a1;
                double* w0 = Wq + sn * PADW + sm;
                double* w1 = Wq + (sn + 32) * PADW + sm;
                #pragma unroll
                for (int i = 0; i < 4; ++i) {
                    w0[i * 8] = (double)f0[i];
                    w1[i * 8] = (double)f1[i];
                }
            }
            // prefetch next A chunk into regs
            if (ch + 1 < NCHUNK) {
                const float* p = Wl + (size_t)(n0b + sn) * DD + k0s + (ch + 1) * KC + 4 * sm;
                a0 = *(const float4*)p;
                a1 = *(const float4*)(p + (size_t)32 * DD);
            }
            __syncthreads();               // W tile visible

            // prefetch next B chunk into regs (VMEM, overlaps compute)
            float bN[8];
            if (ch + 1 < NCHUNK) {
                int k0n = k0s + (ch + 1) * KC;
                #pragma unroll
                for (int j = 0; j < 8; ++j) {
                    int k = k0n + 4 * j + q;
                    int row = idx ? idx[k] : k;
                    bN[j] = srcT[(size_t)row * BB + b0w + c];
                }
            }

            // compute: k_local = 4*(2*jp + h) + q, cols 8q + 2jp (+1)
            #pragma unroll
            for (int jp = 0; jp < 4; ++jp) {
                double2 wf[4];
                #pragma unroll
                for (int tt = 0; tt < 4; ++tt)
                    wf[tt] = *(const double2*)(Wq + (16 * tt + c) * PADW + q * 8 + 2 * jp);
                double bv0 = (double)bF[2 * jp];
                double bv1 = (double)bF[2 * jp + 1];
                #pragma unroll
                for (int tt = 0; tt < 4; ++tt)
                    acc[tt] = __builtin_amdgcn_mfma_f64_16x16x4f64(wf[tt].x, bv0, acc[tt], 0, 0, 0);
                #pragma unroll
                for (int tt = 0; tt < 4; ++tt)
                    acc[tt] = __builtin_amdgcn_mfma_f64_16x16x4f64(wf[tt].y, bv1, acc[tt], 0, 0, 0);
            }
            if (ch + 1 < NCHUNK) {
                #pragma unroll
                for (int j = 0; j < 8; ++j) bF[j] = bN[j];
            }
        }

        // store via probed layout
        #pragma unroll
        for (int tt = 0; tt < 4; ++tt) {
            #pragma unroll
            for (int r = 0; r < 4; ++r) {
                int n = n0b + 16 * tt + rowD[r];
                size_t o = ((size_t)split * NN + n) * BB + b0w + colD[r];
                parts[o] = acc[tt][r];
            }
        }
        grid.sync();

        // ================= spike phase =================
        {
            int i = bid * 256 + t;         // 1024*256 = NB
            double a = 0.0;
            #pragma unroll
            for (int s = 0; s < NSPLIT; ++s)
                a += parts[(size_t)s * NB + i];
            const double th = (double)thresholds[l];
            double m = 0.0;
            int cnt = 0;
            for (int tt = 0; tt < T; ++tt) {
                m += a;
                if (m > th) { cnt++; m -= th; }
            }
            if (l == LL - 1) cntT[i] = (float)cnt;
            else             meanT[i] = (float)cnt / (float)T;
        }
        grid.sync();
    }

    // ---- out phase: out[b, o] = cntT[oidx[o]][b] ----
    if (t < 128) {
        int i = bid * 128 + t;             // 1024*128 = BB*OUTN
        int b = i >> 10;
        int o = i & 1023;
        out[i] = cntT[(size_t)oidx[o] * BB + b];
    }
}

// ===========================================================================
// Fallback path: R4-proven separate kernels (used if cooperative launch is
// rejected by the runtime / graph capture).
// ===========================================================================
__global__ __launch_bounds__(256) void gather0_kernel(
    const float* __restrict__ x, const int* __restrict__ idx0,
    float* __restrict__ At)
{
    int i = blockIdx.x * 256 + threadIdx.x;
    int k = i >> 7;
    int b = i & 127;
    At[i] = x[b * DD + idx0[k]];
}

__global__ __launch_bounds__(256, 4) void gemm_mfma64(
    const float* __restrict__ srcT, const int* __restrict__ idx,
    const float* __restrict__ Wl, double* __restrict__ parts, int krange)
{
    __shared__ __align__(16) double Wq[64 * PADW];

    const int t     = threadIdx.x;
    const int nsup  = blockIdx.x;
    const int bsup  = blockIdx.y;
    const int split = blockIdx.z;
    const int n0b   = nsup * 64;
    const int k0s   = split * krange;
    const int wq    = t >> 6;
    const int lane  = t & 63;
    const int q     = lane >> 4;
    const int c     = lane & 15;
    const int b0w   = bsup * 64 + wq * 16;

    double4v pr = {0., 0., 0., 0.}, pc = {0., 0., 0., 0.};
    pr = __builtin_amdgcn_mfma_f64_16x16x4f64(0.25 * (double)c, 1.0, pr, 0, 0, 0);
    pc = __builtin_amdgcn_mfma_f64_16x16x4f64(0.25, (double)c, pc, 0, 0, 0);
    int rowD[4], colD[4];
    #pragma unroll
    for (int r = 0; r < 4; ++r) {
        rowD[r] = (int)(pr[r] + 0.25);
        colD[r] = (int)(pc[r] + 0.25);
    }

    const int sn = t >> 3;
    const int sm = t & 7;

    double4v acc[4] = {{0.,0.,0.,0.},{0.,0.,0.,0.},{0.,0.,0.,0.},{0.,0.,0.,0.}};

    float4 a0 = *(const float4*)(Wl + (size_t)(n0b + sn) * DD + k0s + 4 * sm);
    float4 a1 = *(const float4*)(Wl + (size_t)(n0b + sn + 32) * DD + k0s + 4 * sm);
    float bF[8];
    #pragma unroll
    for (int j = 0; j < 8; ++j) {
        int k = k0s + 4 * j + q;
        int row = idx ? idx[k] : k;
        bF[j] = srcT[(size_t)row * BB + b0w + c];
    }

    const int nchunk = krange / KC;
    for (int ch = 0; ch < nchunk; ++ch) {
        __syncthreads();
        {
            const float* f0 = (const float*)&a0;
            const float* f1 = (const float*)&a1;
            double* w0 = Wq + sn * PADW + sm;
            double* w1 = Wq + (sn + 32) * PADW + sm;
            #pragma unroll
            for (int i = 0; i < 4; ++i) {
                w0[i * 8] = (double)f0[i];
                w1[i * 8] = (double)f1[i];
            }
        }
        if (ch + 1 < nchunk) {
            const float* p = Wl + (size_t)(n0b + sn) * DD + k0s + (ch + 1) * KC + 4 * sm;
            a0 = *(const float4*)p;
            a1 = *(const float4*)(p + (size_t)32 * DD);
        }
        __syncthreads();

        float bN[8];
        if (ch + 1 < nchunk) {
            int k0n = k0s + (ch + 1) * KC;
            #pragma unroll
            for (int j = 0; j < 8; ++j) {
                int k = k0n + 4 * j + q;
                int row = idx ? idx[k] : k;
                bN[j] = srcT[(size_t)row * BB + b0w + c];
            }
        }

        #pragma unroll
        for (int jp = 0; jp < 4; ++jp) {
            double2 wf[4];
            #pragma unroll
            for (int tt = 0; tt < 4; ++tt)
                wf[tt] = *(const double2*)(Wq + (16 * tt + c) * PADW + q * 8 + 2 * jp);
            double bv0 = (double)bF[2 * jp];
            double bv1 = (double)bF[2 * jp + 1];
            #pragma unroll
            for (int tt = 0; tt < 4; ++tt)
                acc[tt] = __builtin_amdgcn_mfma_f64_16x16x4f64(wf[tt].x, bv0, acc[tt], 0, 0, 0);
            #pragma unroll
            for (int tt = 0; tt < 4; ++tt)
                acc[tt] = __builtin_amdgcn_mfma_f64_16x16x4f64(wf[tt].y, bv1, acc[tt], 0, 0, 0);
        }
        if (ch + 1 < nchunk) {
            #pragma unroll
            for (int j = 0; j < 8; ++j) bF[j] = bN[j];
        }
    }

    #pragma unroll
    for (int tt = 0; tt < 4; ++tt) {
        #pragma unroll
        for (int r = 0; r < 4; ++r) {
            int n = n0b + 16 * tt + rowD[r];
            size_t o = ((size_t)split * NN + n) * BB + b0w + colD[r];
            parts[o] = acc[tt][r];
        }
    }
}

__global__ __launch_bounds__(256) void spike_kernel(
    const double* __restrict__ parts, const float* __restrict__ thresholds,
    int l, const int* __restrict__ Tptr,
    float* __restrict__ meanT, float* __restrict__ cntT, int nsplit)
{
    int i0 = blockIdx.x * 256 + threadIdx.x;
    int i1 = i0 + NB / 2;
    double a0 = 0.0, a1 = 0.0;
    for (int s = 0; s < nsplit; ++s) {
        a0 += parts[(size_t)s * NB + i0];
        a1 += parts[(size_t)s * NB + i1];
    }
    const double thr = (double)thresholds[l];
    const int T = *Tptr;
    double m0 = 0.0, m1 = 0.0;
    int c0 = 0, c1 = 0;
    for (int t = 0; t < T; ++t) {
        m0 += a0;
        m1 += a1;
        if (m0 > thr) { c0++; m0 -= thr; }
        if (m1 > thr) { c1++; m1 -= thr; }
    }
    if (l == LL - 1) {
        cntT[i0] = (float)c0;
        cntT[i1] = (float)c1;
    } else {
        meanT[i0] = (float)c0 / (float)T;
        meanT[i1] = (float)c1 / (float)T;
    }
}

__global__ __launch_bounds__(256) void out_kernel(
    const float* __restrict__ cntT, const int* __restrict__ out_idx,
    float* __restrict__ out)
{
    int i = blockIdx.x * 256 + threadIdx.x;
    int b = i >> 10;
    int o = i & 1023;
    out[i] = cntT[(size_t)out_idx[o] * BB + b];
}

extern "C" void kernel_launch(void* const* d_in, const int* in_sizes, int n_in,
                              void* d_out, int out_size, void* d_ws, size_t ws_size,
                              hipStream_t stream)
{
    const float* x    = (const float*)d_in[0];
    const float* W    = (const float*)d_in[1];
    const float* thr  = (const float*)d_in[2];
    const int*   axon = (const int*)d_in[3];
    const int*   oidx = (const int*)d_in[4];
    const int*   Tptr = (const int*)d_in[5];
    float* out = (float*)d_out;

    char* ws = (char*)d_ws;
    float*  At    = (float*)ws;                    // 1 MB  [D][B]
    float*  meanT = (float*)(ws + (1u << 20));     // 1 MB  [N][B]
    float*  cntT  = (float*)(ws + (2u << 20));     // 1 MB  [N][B]
    double* parts = (double*)(ws + (3u << 20));    // NSPLIT * 2 MB

    const size_t need = (3u << 20) + (size_t)NSPLIT * NB * sizeof(double);

    hipError_t cerr = hipErrorUnknown;
    if (ws_size >= need) {
        void* args[] = { (void*)&x, (void*)&W, (void*)&thr, (void*)&axon,
                         (void*)&oidx, (void*)&Tptr, (void*)&out,
                         (void*)&At, (void*)&meanT, (void*)&cntT, (void*)&parts };
        cerr = hipLaunchCooperativeKernel((void*)mega_kernel,
                                          dim3(1024), dim3(256), args, 0, stream);
    }
    if (cerr != hipSuccess) {
        // -------- fallback: R4-proven multi-kernel path --------
        int nsplit = 16;
        while (nsplit > 1 &&
               (size_t)nsplit * NB * sizeof(double) + (3u << 20) > ws_size)
            nsplit >>= 1;
        const int krange = DD / nsplit;

        gather0_kernel<<<(DD * BB) / 256, 256, 0, stream>>>(x, axon, At);
        for (int l = 0; l < LL; ++l) {
            const float* srcT = (l == 0) ? At : meanT;
            const int*   idx  = (l == 0) ? nullptr : (axon + (size_t)l * DD);
            gemm_mfma64<<<dim3(NN / 64, BB / 64, nsplit), 256, 0, stream>>>(
                srcT, idx, W + (size_t)l * NN * DD, parts, krange);
            spike_kernel<<<NB / 512, 256, 0, stream>>>(
                parts, thr, l, Tptr, meanT, cntT, nsplit);
        }
        out_kernel<<<(BB * OUTN) / 256, 256, 0, stream>>>(cntT, oidx, out);
    }
}

// Round 7
// 459.067 us; speedup vs baseline: 2.8135x; 2.8135x over previous
//
#include <hip/hip_runtime.h>

// Problem constants
#define BB   128
#define DD   2048
#define NN   2048
#define LL   4
#define OUTN 1024
#define KHALF 1024             // K per wk-half (2 halves per block)
#define KCH   64               // k per round per half
#define NROUND (KHALF / KCH)   // 16
#define NSTR  66               // LDS doubles per n-row (64 cols + 2 pad)
#define HSTR  (16 * NSTR)      // per-half LDS stride

typedef double double4v __attribute__((ext_vector_type(4)));

// ---------------------------------------------------------------------------
// Layer-0 transpose-gather: At[k][b] = x[b, axon_idx0[k]]
// ---------------------------------------------------------------------------
__global__ __launch_bounds__(256) void gather0_kernel(
    const float* __restrict__ x, const int* __restrict__ idx0,
    float* __restrict__ At)
{
    int i = blockIdx.x * 256 + threadIdx.x;   // over DD*BB
    int k = i >> 7;
    int b = i & 127;
    At[i] = x[b * DD + idx0[k]];
}

// ---------------------------------------------------------------------------
// Fused layer kernel: GEMM (full K per block) + in-block K-half reduce +
// spike scan + direct meanT/cntT write.  NO split-K workspace, NO spike pass.
// Block: 256 thr = 4 waves = (wb in {0,1} b-half) x (wk in {0,1} K-half).
// Block tile: 16 n x 32 b.  Grid: 128 n-tiles x 4 b-tiles = 512 blocks
// (2 blocks/CU, 2 waves/SIMD).  Wave: 16n x 16b x 1024k = 256 f64 MFMAs in
// 4 independent acc chains.  W staged per-round in LDS (16n x 64k per half,
// stride-66 rows: read conflicts 2-way max = free).  B (src) per-lane global
// loads from L2-resident 1 MB buffer, prefetched one round ahead.
// D-fragment layout discovered at runtime via two probe MFMAs (R4-proven).
// ---------------------------------------------------------------------------
__global__ __launch_bounds__(256, 2) void layer_kernel(
    const float* __restrict__ srcT,   // [2048 rows][BB] fp32
    const int*   __restrict__ idx,    // nullptr => identity rows
    const float* __restrict__ Wl,     // [n][k] row-major
    const float* __restrict__ thresholds, int l,
    const int*   __restrict__ Tptr,
    float* __restrict__ dst, int isLast)
{
    __shared__ __align__(16) double Wd[2 * HSTR];   // 16.9 KB

    const int t = threadIdx.x;
    const int g = blockIdx.x;              // 0..511
    // XCD swizzle: the 4 b-replicas of an n-tile land on the same XCD (g mod 8)
    const int btile = (g >> 3) & 3;
    const int ntile = (g & 7) + 8 * (g >> 5);
    const int n0 = ntile * 16;
    const int b0 = btile * 32;

    const int wq   = t >> 6, lane = t & 63;
    const int wk   = wq >> 1, wb = wq & 1;
    const int q    = lane >> 4, c = lane & 15;
    const int bcol = b0 + 16 * wb + c;

    // staging ids: thread stages row s_n of half s_h, float4 pair sm / sm+8
    const int sm  = t & 7;
    const int s_n = (t >> 3) & 15;
    const int s_h = t >> 7;

    // ---- runtime D-layout probe (layout-agnostic epilogue) ----
    double4v pr = {0., 0., 0., 0.}, pc = {0., 0., 0., 0.};
    pr = __builtin_amdgcn_mfma_f64_16x16x4f64(0.25 * (double)c, 1.0, pr, 0, 0, 0);
    pc = __builtin_amdgcn_mfma_f64_16x16x4f64(0.25, (double)c, pc, 0, 0, 0);
    int rowD[4], colD[4];
    #pragma unroll
    for (int r = 0; r < 4; ++r) {
        rowD[r] = (int)(pr[r] + 0.25);
        colD[r] = (int)(pc[r] + 0.25);
    }

    double4v acc[4] = {{0.,0.,0.,0.},{0.,0.,0.,0.},{0.,0.,0.,0.},{0.,0.,0.,0.}};

    const float*  wrowbase = Wl + (size_t)(n0 + s_n) * DD + KHALF * s_h;
    double*       sbase    = Wd + s_h * HSTR + s_n * NSTR;
    const double* rbase    = Wd + wk * HSTR + c * NSTR + 16 * q;

    // ---- prologue: round-0 A (W float4 pair) + B (16 scalar) ----
    float4 v0 = *(const float4*)(wrowbase + 4 * sm);
    float4 v1 = *(const float4*)(wrowbase + 4 * sm + 32);
    float bF[16], bN[16];
    {
        int kb = KHALF * wk;
        #pragma unroll
        for (int j = 0; j < 16; ++j) {
            int k = kb + 4 * j + q;
            int row = idx ? idx[k] : k;
            bF[j] = srcT[(size_t)row * BB + bcol];
        }
    }

    for (int r = 0; r < NROUND; ++r) {
        __syncthreads();                   // previous round's readers done
        // stage A: k_local = 4*m + comp stored at col comp*16 + m
        sbase[0 * 16 + sm]     = (double)v0.x;
        sbase[1 * 16 + sm]     = (double)v0.y;
        sbase[2 * 16 + sm]     = (double)v0.z;
        sbase[3 * 16 + sm]     = (double)v0.w;
        sbase[0 * 16 + sm + 8] = (double)v1.x;
        sbase[1 * 16 + sm + 8] = (double)v1.y;
        sbase[2 * 16 + sm + 8] = (double)v1.z;
        sbase[3 * 16 + sm + 8] = (double)v1.w;
        // prefetch next-round A
        if (r + 1 < NROUND) {
            const float* p = wrowbase + KCH * (r + 1);
            v0 = *(const float4*)(p + 4 * sm);
            v1 = *(const float4*)(p + 4 * sm + 32);
        }
        __syncthreads();                   // W tile visible
        // prefetch next-round B (overlaps MFMA compute)
        if (r + 1 < NROUND) {
            int kb = KHALF * wk + KCH * (r + 1);
            #pragma unroll
            for (int j = 0; j < 16; ++j) {
                int k = kb + 4 * j + q;
                int row = idx ? idx[k] : k;
                bN[j] = srcT[(size_t)row * BB + bcol];
            }
        }
        // compute: 16 MFMAs, 4 independent chains
        #pragma unroll
        for (int jp = 0; jp < 8; ++jp) {
            double2 wf = *(const double2*)(rbase + 2 * jp);
            acc[jp & 3] = __builtin_amdgcn_mfma_f64_16x16x4f64(
                wf.x, (double)bF[2 * jp], acc[jp & 3], 0, 0, 0);
            acc[jp & 3] = __builtin_amdgcn_mfma_f64_16x16x4f64(
                wf.y, (double)bF[2 * jp + 1], acc[jp & 3], 0, 0, 0);
        }
        if (r + 1 < NROUND) {
            #pragma unroll
            for (int j = 0; j < 16; ++j) bF[j] = bN[j];
        }
    }

    double4v a = (acc[0] + acc[1]) + (acc[2] + acc[3]);

    // ---- in-block K-half reduction via LDS (deterministic order) ----
    __syncthreads();                       // all LDS readers done; reuse Wd
    double* Red = Wd;
    if (wk == 1) {
        double* p = Red + (wb * 64 + lane) * 4;
        p[0] = a[0]; p[1] = a[1]; p[2] = a[2]; p[3] = a[3];
    }
    __syncthreads();
    if (wk == 0) {
        const double* p = Red + (wb * 64 + lane) * 4;
        a[0] += p[0]; a[1] += p[1]; a[2] += p[2]; a[3] += p[3];

        // ---- spike scan (4 independent chains) + write ----
        const double th = (double)thresholds[l];
        const int T = *Tptr;
        const float sc = isLast ? 1.0f : (1.0f / (float)T);  // cnt/T exact fp32
        double m0 = 0., m1 = 0., m2 = 0., m3 = 0.;
        int c0 = 0, c1 = 0, c2 = 0, c3 = 0;
        for (int tt = 0; tt < T; ++tt) {
            m0 += a[0]; if (m0 > th) { c0++; m0 -= th; }
            m1 += a[1]; if (m1 > th) { c1++; m1 -= th; }
            m2 += a[2]; if (m2 > th) { c2++; m2 -= th; }
            m3 += a[3]; if (m3 > th) { c3++; m3 -= th; }
        }
        int cnt[4] = {c0, c1, c2, c3};
        #pragma unroll
        for (int r = 0; r < 4; ++r) {
            int n = n0 + rowD[r];
            dst[(size_t)n * BB + b0 + 16 * wb + colD[r]] = (float)cnt[r] * sc;
        }
    }
}

// ---------------------------------------------------------------------------
// Output gather: out[b, o] = cntT[out_idx[o]][b]
// ---------------------------------------------------------------------------
__global__ __launch_bounds__(256) void out_kernel(
    const float* __restrict__ cntT, const int* __restrict__ out_idx,
    float* __restrict__ out)
{
    int i = blockIdx.x * 256 + threadIdx.x;   // over BB*OUTN
    int b = i >> 10;
    int o = i & 1023;
    out[i] = cntT[(size_t)out_idx[o] * BB + b];
}

extern "C" void kernel_launch(void* const* d_in, const int* in_sizes, int n_in,
                              void* d_out, int out_size, void* d_ws, size_t ws_size,
                              hipStream_t stream)
{
    const float* x    = (const float*)d_in[0];
    const float* W    = (const float*)d_in[1];
    const float* thr  = (const float*)d_in[2];
    const int*   axon = (const int*)d_in[3];
    const int*   oidx = (const int*)d_in[4];
    const int*   Tptr = (const int*)d_in[5];
    float* out = (float*)d_out;

    char* ws = (char*)d_ws;
    float* At   = (float*)ws;                  // 1 MB [2048][128]
    float* mA   = (float*)(ws + (1u << 20));   // 1 MB ping
    float* mB   = (float*)(ws + (2u << 20));   // 1 MB pong
    float* cntT = (float*)(ws + (3u << 20));   // 1 MB

    gather0_kernel<<<(DD * BB) / 256, 256, 0, stream>>>(x, axon, At);

    // ping-pong buffers: no in-place read/write hazard within a layer
    const float* srcs[LL] = { At, mA, mB, mA };
    float*       dsts[LL] = { mA, mB, mA, cntT };
    for (int l = 0; l < LL; ++l) {
        const int* idx = (l == 0) ? nullptr : (axon + (size_t)l * DD);
        layer_kernel<<<512, 256, 0, stream>>>(
            srcs[l], idx, W + (size_t)l * NN * DD, thr, l, Tptr,
            dsts[l], (l == LL - 1) ? 1 : 0);
    }

    out_kernel<<<(BB * OUTN) / 256, 256, 0, stream>>>(cntT, oidx, out);
}